// Round 3
// baseline (639.693 us; speedup 1.0000x reference)
//
#include <hip/hip_runtime.h>
#include <hip/hip_bf16.h>

typedef __hip_bfloat16 bf16;
typedef __attribute__((ext_vector_type(8))) __bf16 bf16x8;
typedef __attribute__((ext_vector_type(4))) float f32x4;

__device__ __forceinline__ f32x4 mfma16(bf16x8 a, bf16x8 b, f32x4 c) {
  return __builtin_amdgcn_mfma_f32_16x16x32_bf16(a, b, c, 0, 0, 0);
}

__device__ __forceinline__ void gload_lds16(const void* g, void* lds) {
  __builtin_amdgcn_global_load_lds(
      (const __attribute__((address_space(1))) unsigned int*)g,
      (__attribute__((address_space(3))) unsigned int*)lds, 16, 0, 0);
}

// ---------------------------------------------------------------------------
// fp32 -> bf16 converters (inputs arrive as fp32; MFMA pipeline runs bf16)
// ---------------------------------------------------------------------------
__global__ __launch_bounds__(256)
void cvt_x_k(const float* __restrict__ s, bf16* __restrict__ d)
{
  const int i = (blockIdx.x * 256 + threadIdx.x) * 8;   // grid sized exactly
  float4 a = *(const float4*)(s + i);
  float4 b = *(const float4*)(s + i + 4);
  union { bf16 h[8]; bf16x8 v; } u;
  u.h[0] = __float2bfloat16(a.x); u.h[1] = __float2bfloat16(a.y);
  u.h[2] = __float2bfloat16(a.z); u.h[3] = __float2bfloat16(a.w);
  u.h[4] = __float2bfloat16(b.x); u.h[5] = __float2bfloat16(b.y);
  u.h[6] = __float2bfloat16(b.z); u.h[7] = __float2bfloat16(b.w);
  *(bf16x8*)(d + i) = u.v;
}

__global__ __launch_bounds__(256)
void cvt_w_k(const float* s0, const float* s1, const float* s2, const float* s3,
             const float* s4, const float* s5, const float* s6, bf16* __restrict__ d)
{
  const int mat = blockIdx.x >> 7, blk = blockIdx.x & 127;   // 7 x 128 blocks
  const float* s;
  switch (mat) {
    case 0: s = s0; break; case 1: s = s1; break; case 2: s = s2; break;
    case 3: s = s3; break; case 4: s = s4; break; case 5: s = s5; break;
    default: s = s6; break;
  }
  const int i = (blk * 256 + threadIdx.x) * 8;               // 262144 elems/mat
  float4 a = *(const float4*)(s + i);
  float4 b = *(const float4*)(s + i + 4);
  union { bf16 h[8]; bf16x8 v; } u;
  u.h[0] = __float2bfloat16(a.x); u.h[1] = __float2bfloat16(a.y);
  u.h[2] = __float2bfloat16(a.z); u.h[3] = __float2bfloat16(a.w);
  u.h[4] = __float2bfloat16(b.x); u.h[5] = __float2bfloat16(b.y);
  u.h[6] = __float2bfloat16(b.z); u.h[7] = __float2bfloat16(b.w);
  *(bf16x8*)(d + mat * 262144 + i) = u.v;
}

// ---------------------------------------------------------------------------
// GEMM: C[m,n] = sum_k A[m,k] * W[n,k] + bias[n]     (A bf16, W bf16, bias f32)
// A: [65536, 512] bf16 row-major. W: up to 3 matrices [512,512] (n selects).
// MODE 0: fp32 store to F0[m*512+n] (out projection -> d_out, float32)
// MODE 1: stage-1 QKV store (bf16), m decoded as natural x token -> (a1, seq)
// MODE 2: stage-2 QKV store (bf16), m = a2*32 + seq (x2 row order)
// Q/K stored [a][h][seq][e]; V stored transposed [a][h][e][seq].
// LDS tiles XOR-swizzled on 16B slots; swizzle applied on the global SOURCE
// address (global_load_lds writes linearly) and on the ds_read address.
// ---------------------------------------------------------------------------
template<int MODE, int NBN>
__global__ __launch_bounds__(256)
void gemm_k(const bf16* __restrict__ A,
            const bf16* __restrict__ W0, const bf16* __restrict__ W1, const bf16* __restrict__ W2,
            const float* __restrict__ Bi0, const float* __restrict__ Bi1, const float* __restrict__ Bi2,
            bf16* __restrict__ O0, bf16* __restrict__ O1, bf16* __restrict__ O2,
            float* __restrict__ F0)
{
  __shared__ __align__(16) bf16 Asw[128 * 64];
  __shared__ __align__(16) bf16 Bsw[128 * 64];

  const int tid  = threadIdx.x;
  const int lane = tid & 63;
  const int w    = tid >> 6;
  const int bm   = blockIdx.x / NBN;
  const int bn   = blockIdx.x % NBN;
  const int m0   = bm * 128;
  const int n0   = bn * 128;

  const bf16* Wsel; const float* Bsel; int nbase;
  if (MODE == 0) { Wsel = W0; Bsel = Bi0; nbase = n0; }
  else {
    const int mat = n0 >> 9; nbase = n0 & 511;
    Wsel = (mat == 0) ? W0 : ((mat == 1) ? W1 : W2);
    Bsel = (mat == 0) ? Bi0 : ((mat == 1) ? Bi1 : Bi2);
  }

  const int lq = lane & 15, qd = lane >> 4;
  const int wr = (w >> 1) * 64, wc = (w & 1) * 64;

  f32x4 acc[4][4];
#pragma unroll
  for (int i = 0; i < 4; ++i)
#pragma unroll
    for (int j = 0; j < 4; ++j) acc[i][j] = f32x4{0.f, 0.f, 0.f, 0.f};

  const int sr    = lane >> 3;  // 0..7 rows within a 1KB chunk
  const int sslot = lane & 7;   // 16B slot within 128B row

  for (int kt = 0; kt < 8; ++kt) {           // K = 512, BK = 64
#pragma unroll
    for (int j = 0; j < 4; ++j) {
      const int L0 = (w * 4 + j) * 1024;     // wave-uniform LDS byte base
      const int rr = (w * 4 + j) * 8 + sr;   // tile row this lane stages
      const int cb = kt * 128 + ((sslot ^ (rr & 7)) << 4);  // pre-swizzled global byte col
      gload_lds16((const char*)A    + (size_t)(m0 + rr)    * 1024 + cb, (char*)Asw + L0);
      gload_lds16((const char*)Wsel + (size_t)(nbase + rr) * 1024 + cb, (char*)Bsw + L0);
    }
    __syncthreads();
#pragma unroll
    for (int ks = 0; ks < 2; ++ks) {
      bf16x8 af[4], bfr[4];
#pragma unroll
      for (int mi = 0; mi < 4; ++mi) {
        const int row = wr + mi * 16 + lq;
        const int kb  = (ks * 64 + qd * 16) ^ ((row & 7) << 4);
        af[mi] = *(const bf16x8*)((const char*)Asw + row * 128 + kb);
      }
#pragma unroll
      for (int ni = 0; ni < 4; ++ni) {
        const int row = wc + ni * 16 + lq;
        const int kb  = (ks * 64 + qd * 16) ^ ((row & 7) << 4);
        bfr[ni] = *(const bf16x8*)((const char*)Bsw + row * 128 + kb);
      }
#pragma unroll
      for (int mi = 0; mi < 4; ++mi)
#pragma unroll
        for (int ni = 0; ni < 4; ++ni)
          acc[mi][ni] = mfma16(af[mi], bfr[ni], acc[mi][ni]);
    }
    __syncthreads();
  }

  float biasv[4];
  int ncol[4];
#pragma unroll
  for (int ni = 0; ni < 4; ++ni) {
    const int n = n0 + wc + ni * 16 + lq;
    ncol[ni] = n;
    const int nn = (MODE == 0) ? n : (n & 511);
    biasv[ni] = Bsel[nn];
  }

#pragma unroll
  for (int mi = 0; mi < 4; ++mi) {
#pragma unroll
    for (int r = 0; r < 4; ++r) {
      const int m = m0 + wr + mi * 16 + qd * 4 + r;
      if (MODE == 0) {
#pragma unroll
        for (int ni = 0; ni < 4; ++ni)
          F0[(size_t)m * 512 + ncol[ni]] = acc[mi][ni][r] + biasv[ni];
      } else {
        int a, seq;
        if (MODE == 1) {
          const int b = m >> 13, c = (m >> 3) & 1023, p = m & 7;
          a = (b * 32 + (c >> 5)) * 8 + p;  seq = c & 31;
        } else {
          a = m >> 5;  seq = m & 31;
        }
#pragma unroll
        for (int ni = 0; ni < 4; ++ni) {
          const int n  = ncol[ni];
          const int nn = n & 511, h = nn >> 6, e = nn & 63;
          const bf16 v = __float2bfloat16(acc[mi][ni][r] + biasv[ni]);
          const int mat = n >> 9;
          if (mat == 0)      O0[((size_t)((a * 8 + h) * 32 + seq)) * 64 + e] = v;
          else if (mat == 1) O1[((size_t)((a * 8 + h) * 32 + seq)) * 64 + e] = v;
          else               O2[((size_t)((a * 8 + h) * 64 + e)) * 32 + seq] = v;
        }
      }
    }
  }
}

// ---------------------------------------------------------------------------
// Attention: one wave = one (a, h) task. L=32 keys/queries, E=64.
// Q,K: [a][h][32][64]; V: [a][h][64][32] (transposed).
// scores = Q K^T * 0.125; softmax over keys (shfl_xor within 16-lane groups;
// each group owns distinct q rows); P -> LDS (stride 80B) -> A-fragment;
// PV on MFMA; divide by denom at the end.
// STAGE 1 writes x2 row order; STAGE 2 writes natural token order.
// ---------------------------------------------------------------------------
template<int STAGE>
__global__ __launch_bounds__(256)
void attn_k(const bf16* __restrict__ Q, const bf16* __restrict__ K,
            const bf16* __restrict__ V, bf16* __restrict__ Y)
{
  __shared__ __align__(16) char Plds[4][32 * 80];
  const int tid  = threadIdx.x;
  const int lane = tid & 63;
  const int w    = tid >> 6;
  const int task = blockIdx.x * 4 + w;   // 16384 tasks
  const int a = task >> 3, h = task & 7;
  const int lq = lane & 15, qd = lane >> 4;

  const bf16* Qb = Q + (size_t)(a * 8 + h) * 2048;
  const bf16* Kb = K + (size_t)(a * 8 + h) * 2048;
  const bf16* Vb = V + (size_t)(a * 8 + h) * 2048;

  bf16x8 qf[2][2], kf[2][2];
#pragma unroll
  for (int mi = 0; mi < 2; ++mi)
#pragma unroll
    for (int ks = 0; ks < 2; ++ks) {
      qf[mi][ks] = *(const bf16x8*)(Qb + (mi * 16 + lq) * 64 + ks * 32 + qd * 8);
      kf[mi][ks] = *(const bf16x8*)(Kb + (mi * 16 + lq) * 64 + ks * 32 + qd * 8);
    }

  f32x4 s[2][2];
#pragma unroll
  for (int mi = 0; mi < 2; ++mi)
#pragma unroll
    for (int ni = 0; ni < 2; ++ni) {
      s[mi][ni] = f32x4{0.f, 0.f, 0.f, 0.f};
#pragma unroll
      for (int ks = 0; ks < 2; ++ks)
        s[mi][ni] = mfma16(qf[mi][ks], kf[ni][ks], s[mi][ni]);
    }

  char* Pw = Plds[w];
  float rden[2][4];
#pragma unroll
  for (int mi = 0; mi < 2; ++mi) {
#pragma unroll
    for (int r = 0; r < 4; ++r) {
      float v0 = s[mi][0][r] * 0.125f, v1 = s[mi][1][r] * 0.125f;
      float mx = fmaxf(v0, v1);
#pragma unroll
      for (int d = 1; d < 16; d <<= 1) mx = fmaxf(mx, __shfl_xor(mx, d, 64));
      const float p0 = __expf(v0 - mx), p1 = __expf(v1 - mx);
      float sm = p0 + p1;
#pragma unroll
      for (int d = 1; d < 16; d <<= 1) sm += __shfl_xor(sm, d, 64);
      rden[mi][r] = 1.f / sm;
      const int qrow = mi * 16 + qd * 4 + r;
      bf16* prow = (bf16*)(Pw + qrow * 80);
      prow[lq]      = __float2bfloat16(p0);
      prow[16 + lq] = __float2bfloat16(p1);
    }
  }
  // Cross-lane LDS RAW within the wave: force DS completion and block
  // scheduler reordering (rule #18).
  asm volatile("s_waitcnt lgkmcnt(0)" ::: "memory");
  __builtin_amdgcn_sched_barrier(0);

  bf16x8 pf[2], vf[4];
#pragma unroll
  for (int mi = 0; mi < 2; ++mi)
    pf[mi] = *(const bf16x8*)(Pw + (mi * 16 + lq) * 80 + qd * 16);
#pragma unroll
  for (int ni = 0; ni < 4; ++ni)
    vf[ni] = *(const bf16x8*)(Vb + (ni * 16 + lq) * 32 + qd * 8);

  f32x4 o[2][4];
#pragma unroll
  for (int mi = 0; mi < 2; ++mi)
#pragma unroll
    for (int ni = 0; ni < 4; ++ni) {
      o[mi][ni] = f32x4{0.f, 0.f, 0.f, 0.f};
      o[mi][ni] = mfma16(pf[mi], vf[ni], o[mi][ni]);
    }

  int rowbase;
  if (STAGE == 1) { const int p = a & 7, ng = (a >> 3) & 31, b = a >> 8; rowbase = b * 8192 + p * 32 + ng; }
  else            { const int p = a & 7, i  = (a >> 3) & 31, b = a >> 8; rowbase = b * 8192 + i * 8 + p; }

#pragma unroll
  for (int mi = 0; mi < 2; ++mi) {
#pragma unroll
    for (int r = 0; r < 4; ++r) {
      const int q   = mi * 16 + qd * 4 + r;
      const int row = rowbase + q * 256;
      const float rd = rden[mi][r];
#pragma unroll
      for (int ni = 0; ni < 4; ++ni) {
        const int e = ni * 16 + lq;
        Y[(size_t)row * 512 + h * 64 + e] = __float2bfloat16(o[mi][ni][r] * rd);
      }
    }
  }
}

// ---------------------------------------------------------------------------
extern "C" void kernel_launch(void* const* d_in, const int* in_sizes, int n_in,
                              void* d_out, int out_size, void* d_ws, size_t ws_size,
                              hipStream_t stream) {
  const float* x   = (const float*)d_in[0];
  const float* q1w = (const float*)d_in[1];
  const float* q1b = (const float*)d_in[2];
  const float* k1w = (const float*)d_in[3];
  const float* k1b = (const float*)d_in[4];
  const float* v1w = (const float*)d_in[5];
  const float* v1b = (const float*)d_in[6];
  const float* q2w = (const float*)d_in[7];
  const float* q2b = (const float*)d_in[8];
  const float* k2w = (const float*)d_in[9];
  const float* k2b = (const float*)d_in[10];
  const float* v2w = (const float*)d_in[11];
  const float* v2b = (const float*)d_in[12];
  const float* ow  = (const float*)d_in[13];
  const float* ob  = (const float*)d_in[14];
  float* out = (float*)d_out;   // reference output dtype is float32

  const size_t TOK = 65536ull * 512ull;  // 33.5M elems = 64MB bf16
  const size_t WS1 = 262144;             // one 512x512 weight matrix
  bf16* Xbf = (bf16*)d_ws;               // stage-1 input; later reused as X2
  bf16* Qb  = Xbf + TOK;
  bf16* Kb  = Qb + TOK;
  bf16* Vb  = Kb + TOK;
  bf16* Wbf = Vb + TOK;                  // 7 x 512x512 bf16 (order: q1,k1,v1,q2,k2,v2,ow)
  bf16* X2  = Xbf;                       // Xbf dead after gemm<1> reads it

  // fp32 -> bf16 conversions
  cvt_x_k<<<16384, 256, 0, stream>>>(x, Xbf);
  cvt_w_k<<<7 * 128, 256, 0, stream>>>(q1w, k1w, v1w, q2w, k2w, v2w, ow, Wbf);

  // stage 1: QKV + attention (writes X2 in stage-2 row order)
  gemm_k<1, 12><<<512 * 12, 256, 0, stream>>>(Xbf, Wbf, Wbf + WS1, Wbf + 2 * WS1,
                                              q1b, k1b, v1b, Qb, Kb, Vb, nullptr);
  attn_k<1><<<4096, 256, 0, stream>>>(Qb, Kb, Vb, X2);
  // stage 2: QKV + attention (reuses QKV slots; writes natural token order)
  gemm_k<2, 12><<<512 * 12, 256, 0, stream>>>(X2, Wbf + 3 * WS1, Wbf + 4 * WS1, Wbf + 5 * WS1,
                                              q2b, k2b, v2b, Qb, Kb, Vb, nullptr);
  attn_k<2><<<4096, 256, 0, stream>>>(Qb, Kb, Vb, X2);
  // output projection -> d_out (fp32)
  gemm_k<0, 4><<<512 * 4, 256, 0, stream>>>(X2, Wbf + 6 * WS1, Wbf + 6 * WS1, Wbf + 6 * WS1,
                                            ob, ob, ob, nullptr, nullptr, nullptr, out);
}

// Round 5
// 462.730 us; speedup vs baseline: 1.3824x; 1.3824x over previous
//
#include <hip/hip_runtime.h>
#include <hip/hip_bf16.h>

typedef __hip_bfloat16 bf16;
typedef __attribute__((ext_vector_type(8))) __bf16 bf16x8;
typedef __attribute__((ext_vector_type(4))) float f32x4;

__device__ __forceinline__ f32x4 mfma16(bf16x8 a, bf16x8 b, f32x4 c) {
  return __builtin_amdgcn_mfma_f32_16x16x32_bf16(a, b, c, 0, 0, 0);
}

__device__ __forceinline__ void gload_lds16(const void* g, void* lds) {
  __builtin_amdgcn_global_load_lds(
      (const __attribute__((address_space(1))) unsigned int*)g,
      (__attribute__((address_space(3))) unsigned int*)lds, 16, 0, 0);
}

// ---------------------------------------------------------------------------
// fp32 -> bf16 converters
// ---------------------------------------------------------------------------
__global__ __launch_bounds__(256)
void cvt_x_k(const float* __restrict__ s, bf16* __restrict__ d)
{
  const int i = (blockIdx.x * 256 + threadIdx.x) * 8;
  float4 a = *(const float4*)(s + i);
  float4 b = *(const float4*)(s + i + 4);
  union { bf16 h[8]; bf16x8 v; } u;
  u.h[0] = __float2bfloat16(a.x); u.h[1] = __float2bfloat16(a.y);
  u.h[2] = __float2bfloat16(a.z); u.h[3] = __float2bfloat16(a.w);
  u.h[4] = __float2bfloat16(b.x); u.h[5] = __float2bfloat16(b.y);
  u.h[6] = __float2bfloat16(b.z); u.h[7] = __float2bfloat16(b.w);
  *(bf16x8*)(d + i) = u.v;
}

__global__ __launch_bounds__(256)
void cvt_w_k(const float* s0, const float* s1, const float* s2, const float* s3,
             const float* s4, const float* s5, const float* s6, bf16* __restrict__ d)
{
  const int mat = blockIdx.x >> 7, blk = blockIdx.x & 127;
  const float* s;
  switch (mat) {
    case 0: s = s0; break; case 1: s = s1; break; case 2: s = s2; break;
    case 3: s = s3; break; case 4: s = s4; break; case 5: s = s5; break;
    default: s = s6; break;
  }
  const int i = (blk * 256 + threadIdx.x) * 8;
  float4 a = *(const float4*)(s + i);
  float4 b = *(const float4*)(s + i + 4);
  union { bf16 h[8]; bf16x8 v; } u;
  u.h[0] = __float2bfloat16(a.x); u.h[1] = __float2bfloat16(a.y);
  u.h[2] = __float2bfloat16(a.z); u.h[3] = __float2bfloat16(a.w);
  u.h[4] = __float2bfloat16(b.x); u.h[5] = __float2bfloat16(b.y);
  u.h[6] = __float2bfloat16(b.z); u.h[7] = __float2bfloat16(b.w);
  *(bf16x8*)(d + mat * 262144 + i) = u.v;
}

// ---------------------------------------------------------------------------
// GEMM: C[m,n] = A[m,:]·W[n,:] + bias[n].  A:[65536,512] bf16, W: up to 3
// [512,512] mats (n selects).  Double-buffered LDS (T3-min prefetch: STAGE
// next K-tile BEFORE compute; one barrier/K-step), T5 setprio, T1 XCD
// swizzle, XOR-swizzled LDS (both-sides).
// MODE 0: fp32 direct store (out projection -> d_out)
// MODE 1/2: bf16 store in natural [a][h][seq][e] layout for Q,K,V via
//           LDS-staged coalesced epilogue; m-decode differs per stage.
// ---------------------------------------------------------------------------
template<int MODE, int NBN>
__global__ __launch_bounds__(256)
void gemm_k(const bf16* __restrict__ A,
            const bf16* __restrict__ W0, const bf16* __restrict__ W1, const bf16* __restrict__ W2,
            const float* __restrict__ Bi0, const float* __restrict__ Bi1, const float* __restrict__ Bi2,
            bf16* __restrict__ O0, bf16* __restrict__ O1, bf16* __restrict__ O2,
            float* __restrict__ F0)
{
  __shared__ __align__(16) char smem[65536];
  bf16* const Ab0 = (bf16*)smem;
  bf16* const Ab1 = (bf16*)(smem + 16384);
  bf16* const Bb0 = (bf16*)(smem + 32768);
  bf16* const Bb1 = (bf16*)(smem + 49152);

  const int tid  = threadIdx.x;
  const int lane = tid & 63;
  const int w    = tid >> 6;

  // T1: XCD-contiguous bm stripes (grid % 8 == 0 for all modes used)
  const int per = gridDim.x >> 3;
  const int logical = (blockIdx.x & 7) * per + (blockIdx.x >> 3);
  const int bm = logical / NBN;
  const int bn = logical % NBN;
  const int m0 = bm * 128;
  const int n0 = bn * 128;

  const bf16* Wsel; const float* Bsel;
  int nbase;
  if (MODE == 0) { Wsel = W0; Bsel = Bi0; nbase = n0; }
  else {
    const int mat = n0 >> 9; nbase = n0 & 511;
    Wsel = (mat == 0) ? W0 : ((mat == 1) ? W1 : W2);
    Bsel = (mat == 0) ? Bi0 : ((mat == 1) ? Bi1 : Bi2);
  }

  const int lq = lane & 15, qd = lane >> 4;
  const int wr = (w >> 1) * 64, wc = (w & 1) * 64;
  const int sr    = lane >> 3;   // 0..7
  const int sslot = lane & 7;    // 16B slot in 128B row

  f32x4 acc[4][4];
#pragma unroll
  for (int i = 0; i < 4; ++i)
#pragma unroll
    for (int j = 0; j < 4; ++j) acc[i][j] = f32x4{0.f, 0.f, 0.f, 0.f};

  // stage K-tile kt into (Abuf,Bbuf)
  auto STAGE = [&](bf16* Abuf, bf16* Bbuf, int kt) {
#pragma unroll
    for (int j = 0; j < 4; ++j) {
      const int L0 = (w * 4 + j) * 1024;
      const int rr = (w * 4 + j) * 8 + sr;
      const int cb = kt * 128 + ((sslot ^ (rr & 7)) << 4);
      gload_lds16((const char*)A    + (size_t)(m0 + rr)    * 1024 + cb, (char*)Abuf + L0);
      gload_lds16((const char*)Wsel + (size_t)(nbase + rr) * 1024 + cb, (char*)Bbuf + L0);
    }
  };

  STAGE(Ab0, Bb0, 0);
  __syncthreads();                       // compiler drains vmcnt before barrier

  for (int kt = 0; kt < 8; ++kt) {       // K = 512, BK = 64
    const bf16* Ac = (kt & 1) ? Ab1 : Ab0;
    const bf16* Bc = (kt & 1) ? Bb1 : Bb0;
    bf16* An = (kt & 1) ? Ab0 : Ab1;
    bf16* Bn = (kt & 1) ? Bb0 : Bb1;
    if (kt < 7) STAGE(An, Bn, kt + 1);   // prefetch BEFORE compute (T3-min)

#pragma unroll
    for (int ks = 0; ks < 2; ++ks) {
      bf16x8 af[4], bfr[4];
#pragma unroll
      for (int mi = 0; mi < 4; ++mi) {
        const int row = wr + mi * 16 + lq;
        const int kb  = (ks * 64 + qd * 16) ^ ((row & 7) << 4);
        af[mi] = *(const bf16x8*)((const char*)Ac + row * 128 + kb);
      }
#pragma unroll
      for (int ni = 0; ni < 4; ++ni) {
        const int row = wc + ni * 16 + lq;
        const int kb  = (ks * 64 + qd * 16) ^ ((row & 7) << 4);
        bfr[ni] = *(const bf16x8*)((const char*)Bc + row * 128 + kb);
      }
      __builtin_amdgcn_s_setprio(1);
#pragma unroll
      for (int mi = 0; mi < 4; ++mi)
#pragma unroll
        for (int ni = 0; ni < 4; ++ni)
          acc[mi][ni] = mfma16(af[mi], bfr[ni], acc[mi][ni]);
      __builtin_amdgcn_s_setprio(0);
    }
    __syncthreads();                     // vmcnt+lgkm drained here (compiler)
  }

  float biasv[4];
#pragma unroll
  for (int ni = 0; ni < 4; ++ni) {
    const int n = n0 + wc + ni * 16 + lq;
    const int nn = (MODE == 0) ? n : (n & 511);
    biasv[ni] = Bsel[nn];
  }

  if (MODE == 0) {
    // direct fp32 stores: 16 lanes consecutive cols -> 64B segments
#pragma unroll
    for (int mi = 0; mi < 4; ++mi)
#pragma unroll
      for (int r = 0; r < 4; ++r) {
        const int m = m0 + wr + mi * 16 + qd * 4 + r;
#pragma unroll
        for (int ni = 0; ni < 4; ++ni)
          F0[(size_t)m * 512 + (n0 + wc + ni * 16 + lq)] = acc[mi][ni][r] + biasv[ni];
      }
  } else {
    // LDS-staged coalesced epilogue: Ct[128][136] bf16 (272B row stride)
    bf16* const Ct = (bf16*)smem;        // safe: loop ended with barrier
#pragma unroll
    for (int mi = 0; mi < 4; ++mi)
#pragma unroll
      for (int r = 0; r < 4; ++r) {
        const int row = wr + mi * 16 + qd * 4 + r;
#pragma unroll
        for (int ni = 0; ni < 4; ++ni)
          Ct[row * 136 + wc + ni * 16 + lq] = __float2bfloat16(acc[mi][ni][r] + biasv[ni]);
      }
    __syncthreads();

    const int mat = n0 >> 9;
    bf16* const Om = (mat == 0) ? O0 : ((mat == 1) ? O1 : O2);
    const int h0 = (n0 & 511) >> 6;      // first head of this 128-col chunk
    const int sub = tid & 7;
#pragma unroll
    for (int p = 0; p < 8; ++p) {
      const int gid  = p * 32 + (tid >> 3);   // 0..255
      const int hsel = gid >> 7;
      const int mrow = gid & 127;
      const bf16x8 val = *(const bf16x8*)(Ct + mrow * 136 + hsel * 64 + sub * 8);
      const int m = m0 + mrow;
      int a, seq;
      if (MODE == 1) {
        const int b = m >> 13, c = (m >> 3) & 1023, pp = m & 7;
        a = (b * 32 + (c >> 5)) * 8 + pp;  seq = c & 31;
      } else {
        a = m >> 5;  seq = m & 31;
      }
      *(bf16x8*)(Om + ((size_t)((a * 8 + h0 + hsel) * 32 + seq)) * 64 + sub * 8) = val;
    }
  }
}

// ---------------------------------------------------------------------------
// Attention: one wave = one (a,h) task. L=32, E=64.
// Q,K,V all natural [a][h][32][64]. V transposed through padded LDS
// (row stride 132B -> conflict-spread u16 reads).
// ---------------------------------------------------------------------------
template<int STAGE>
__global__ __launch_bounds__(256)
void attn_k(const bf16* __restrict__ Q, const bf16* __restrict__ K,
            const bf16* __restrict__ V, bf16* __restrict__ Y)
{
  __shared__ __align__(16) char Plds[4][32 * 80];
  __shared__ __align__(16) char Vlds[4][32 * 132];
  const int tid  = threadIdx.x;
  const int lane = tid & 63;
  const int w    = tid >> 6;
  const int task = blockIdx.x * 4 + w;   // 16384 tasks
  const int a = task >> 3, h = task & 7;
  const int lq = lane & 15, qd = lane >> 4;

  const bf16* Qb = Q + (size_t)(a * 8 + h) * 2048;
  const bf16* Kb = K + (size_t)(a * 8 + h) * 2048;
  const bf16* Vb = V + (size_t)(a * 8 + h) * 2048;

  // --- stage V rows into padded LDS (transposed reads later) ---
  // 2 lanes per row; each lane stages 32 contiguous elems (64B) of its row.
  {
    const int r  = lane >> 1;            // 0..31
    const int c0 = (lane & 1) * 32;      // elems: 0..31 or 32..63
    union { bf16x8 v; unsigned u[4]; } t0, t1, t2, t3;
    t0.v = *(const bf16x8*)(Vb + r * 64 + c0);
    t1.v = *(const bf16x8*)(Vb + r * 64 + c0 + 8);
    t2.v = *(const bf16x8*)(Vb + r * 64 + c0 + 16);
    t3.v = *(const bf16x8*)(Vb + r * 64 + c0 + 24);
    unsigned* dst = (unsigned*)(Vlds[w] + r * 132 + c0 * 2);
#pragma unroll
    for (int j = 0; j < 4; ++j) dst[j]      = t0.u[j];
#pragma unroll
    for (int j = 0; j < 4; ++j) dst[4 + j]  = t1.u[j];
#pragma unroll
    for (int j = 0; j < 4; ++j) dst[8 + j]  = t2.u[j];
#pragma unroll
    for (int j = 0; j < 4; ++j) dst[12 + j] = t3.u[j];
  }

  bf16x8 qf[2][2], kf[2][2];
#pragma unroll
  for (int mi = 0; mi < 2; ++mi)
#pragma unroll
    for (int ks = 0; ks < 2; ++ks) {
      qf[mi][ks] = *(const bf16x8*)(Qb + (mi * 16 + lq) * 64 + ks * 32 + qd * 8);
      kf[mi][ks] = *(const bf16x8*)(Kb + (mi * 16 + lq) * 64 + ks * 32 + qd * 8);
    }

  f32x4 s[2][2];
#pragma unroll
  for (int mi = 0; mi < 2; ++mi)
#pragma unroll
    for (int ni = 0; ni < 2; ++ni) {
      s[mi][ni] = f32x4{0.f, 0.f, 0.f, 0.f};
#pragma unroll
      for (int ks = 0; ks < 2; ++ks)
        s[mi][ni] = mfma16(qf[mi][ks], kf[ni][ks], s[mi][ni]);
    }

  char* Pw = Plds[w];
  float rden[2][4];
#pragma unroll
  for (int mi = 0; mi < 2; ++mi) {
#pragma unroll
    for (int r = 0; r < 4; ++r) {
      float v0 = s[mi][0][r] * 0.125f, v1 = s[mi][1][r] * 0.125f;
      float mx = fmaxf(v0, v1);
#pragma unroll
      for (int d = 1; d < 16; d <<= 1) mx = fmaxf(mx, __shfl_xor(mx, d, 64));
      const float p0 = __expf(v0 - mx), p1 = __expf(v1 - mx);
      float sm = p0 + p1;
#pragma unroll
      for (int d = 1; d < 16; d <<= 1) sm += __shfl_xor(sm, d, 64);
      rden[mi][r] = 1.f / sm;
      const int qrow = mi * 16 + qd * 4 + r;
      bf16* prow = (bf16*)(Pw + qrow * 80);
      prow[lq]      = __float2bfloat16(p0);
      prow[16 + lq] = __float2bfloat16(p1);
    }
  }
  // same-wave LDS RAW (P and V): drain DS, block reordering (rule #18)
  asm volatile("s_waitcnt lgkmcnt(0)" ::: "memory");
  __builtin_amdgcn_sched_barrier(0);

  bf16x8 pf[2];
#pragma unroll
  for (int mi = 0; mi < 2; ++mi)
    pf[mi] = *(const bf16x8*)(Pw + (mi * 16 + lq) * 80 + qd * 16);

  bf16x8 vf[4];
#pragma unroll
  for (int ni = 0; ni < 4; ++ni) {
    union { bf16 h[8]; bf16x8 v; } uv;
#pragma unroll
    for (int j = 0; j < 8; ++j)
      uv.h[j] = *(const bf16*)(Vlds[w] + (qd * 8 + j) * 132 + (ni * 16 + lq) * 2);
    vf[ni] = uv.v;
  }

  f32x4 o[2][4];
#pragma unroll
  for (int mi = 0; mi < 2; ++mi)
#pragma unroll
    for (int ni = 0; ni < 4; ++ni) {
      o[mi][ni] = f32x4{0.f, 0.f, 0.f, 0.f};
      o[mi][ni] = mfma16(pf[mi], vf[ni], o[mi][ni]);
    }

  int rowbase;
  if (STAGE == 1) { const int p = a & 7, ng = (a >> 3) & 31, b = a >> 8; rowbase = b * 8192 + p * 32 + ng; }
  else            { const int p = a & 7, i  = (a >> 3) & 31, b = a >> 8; rowbase = b * 8192 + i * 8 + p; }

#pragma unroll
  for (int mi = 0; mi < 2; ++mi) {
#pragma unroll
    for (int r = 0; r < 4; ++r) {
      const int q   = mi * 16 + qd * 4 + r;
      const int row = rowbase + q * 256;
      const float rd = rden[mi][r];
#pragma unroll
      for (int ni = 0; ni < 4; ++ni) {
        const int e = ni * 16 + lq;
        Y[(size_t)row * 512 + h * 64 + e] = __float2bfloat16(o[mi][ni][r] * rd);
      }
    }
  }
}

// ---------------------------------------------------------------------------
extern "C" void kernel_launch(void* const* d_in, const int* in_sizes, int n_in,
                              void* d_out, int out_size, void* d_ws, size_t ws_size,
                              hipStream_t stream) {
  const float* x   = (const float*)d_in[0];
  const float* q1w = (const float*)d_in[1];
  const float* q1b = (const float*)d_in[2];
  const float* k1w = (const float*)d_in[3];
  const float* k1b = (const float*)d_in[4];
  const float* v1w = (const float*)d_in[5];
  const float* v1b = (const float*)d_in[6];
  const float* q2w = (const float*)d_in[7];
  const float* q2b = (const float*)d_in[8];
  const float* k2w = (const float*)d_in[9];
  const float* k2b = (const float*)d_in[10];
  const float* v2w = (const float*)d_in[11];
  const float* v2b = (const float*)d_in[12];
  const float* ow  = (const float*)d_in[13];
  const float* ob  = (const float*)d_in[14];
  float* out = (float*)d_out;

  const size_t TOK = 65536ull * 512ull;
  const size_t WS1 = 262144;
  bf16* Xbf = (bf16*)d_ws;
  bf16* Qb  = Xbf + TOK;
  bf16* Kb  = Qb + TOK;
  bf16* Vb  = Kb + TOK;
  bf16* Wbf = Vb + TOK;   // 7 x 512x512 (q1,k1,v1,q2,k2,v2,ow)
  bf16* X2  = Xbf;

  cvt_x_k<<<16384, 256, 0, stream>>>(x, Xbf);
  cvt_w_k<<<7 * 128, 256, 0, stream>>>(q1w, k1w, v1w, q2w, k2w, v2w, ow, Wbf);

  gemm_k<1, 12><<<512 * 12, 256, 0, stream>>>(Xbf, Wbf, Wbf + WS1, Wbf + 2 * WS1,
                                              q1b, k1b, v1b, Qb, Kb, Vb, nullptr);
  attn_k<1><<<4096, 256, 0, stream>>>(Qb, Kb, Vb, X2);
  gemm_k<2, 12><<<512 * 12, 256, 0, stream>>>(X2, Wbf + 3 * WS1, Wbf + 4 * WS1, Wbf + 5 * WS1,
                                              q2b, k2b, v2b, Qb, Kb, Vb, nullptr);
  attn_k<2><<<4096, 256, 0, stream>>>(Qb, Kb, Vb, X2);
  gemm_k<0, 4><<<512 * 4, 256, 0, stream>>>(X2, Wbf + 6 * WS1, Wbf + 6 * WS1, Wbf + 6 * WS1,
                                            ob, ob, ob, nullptr, nullptr, nullptr, out);
}